// Round 11
// baseline (94.292 us; speedup 1.0000x reference)
//
#include <hip/hip_runtime.h>
#include <math.h>

#define B_ 8
#define N_ 2048
#define H_ 256

// One-shot: W1T[k][o] = W1[o][k] (f32, 256 KB in d_ws) -> unit-stride lane
// reads in s_kernel.
__global__ __launch_bounds__(256)
void transpose_w1(const float* __restrict__ W1, float* __restrict__ W1T) {
    W1T[(size_t)blockIdx.x * H_ + threadIdx.x] =
        W1[(size_t)threadIdx.x * H_ + blockIdx.x];
}

// Kernel A: s[m] = sum_o w2[o] * silu( dot(h[m,:], W1[o,:]) + b1[o] ), f64.
// No LDS, no barriers. Block = 4 waves; wave owns 4 rows x ALL 256 o;
// lane owns 4 o's. h rows are wave-uniform -> read via the SCALAR cache
// (s_load, readfirstlane-uniform base), ping-ponged in SGPRs. W1T float4
// per k, 8-k ping-pong in VGPRs (512-cy FMA window covers L2 latency).
// Round-9 analysis: the h-broadcast LDS stream cost ~41 us of shared
// LDS-pipe time per CU; the scalar pipe was idle. waves_per_eu(2,4)
// keeps the allocator off the 52-VGPR spill regime (rounds 3-5).
__global__ __launch_bounds__(256)
__attribute__((amdgpu_waves_per_eu(2, 4)))
void s_kernel(const float* __restrict__ hp, const float* __restrict__ W1T,
              const float* __restrict__ b1, const float* __restrict__ w2,
              double* __restrict__ s_out) {
    const int t = threadIdx.x;
    const int lane = t & 63;
    const int wave = __builtin_amdgcn_readfirstlane(t >> 6);
    const int m0 = blockIdx.x * 16 + wave * 4;   // this wave's 4 rows
    const int o0 = lane * 4;                     // this lane's 4 o's

    const float* hr = hp + (size_t)m0 * H_;      // uniform: rows at +r*H_
    const float* wp = W1T + o0;                  // k-row at wp + k*H_

    double acc[4][4];                            // [o_j][row_r]
    #pragma unroll
    for (int j = 0; j < 4; ++j)
        #pragma unroll
        for (int r = 0; r < 4; ++r) acc[j][r] = 0.0;

    float4 wA[8], wB[8];      // W1T chunk: 8 k x lane's 4 o's (VGPR)
    float hA[32], hB[32];     // h chunk: 4 rows x 8 k, wave-uniform (SGPR)

    #define LOADW(dst, kcv)                                                   \
        do {                                                                  \
            _Pragma("unroll")                                                 \
            for (int kk = 0; kk < 8; ++kk)                                    \
                dst[kk] = *reinterpret_cast<const float4*>(                   \
                    wp + (size_t)((kcv) + kk) * H_);                          \
        } while (0)

    #define LOADH(dst, kcv)                                                   \
        do {                                                                  \
            _Pragma("unroll")                                                 \
            for (int r = 0; r < 4; ++r)                                       \
                _Pragma("unroll")                                             \
                for (int kk = 0; kk < 8; ++kk)                                \
                    dst[r * 8 + kk] = hr[r * H_ + (kcv) + kk];                \
        } while (0)

    // 16 FMAs per k (4 o x 4 rows); 8 k per chunk.
    #define COMPUTE(wv, hbuf)                                                 \
        do {                                                                  \
            _Pragma("unroll")                                                 \
            for (int kk = 0; kk < 8; ++kk) {                                  \
                const double h0 = (double)hbuf[0 * 8 + kk];                   \
                const double h1 = (double)hbuf[1 * 8 + kk];                   \
                const double h2 = (double)hbuf[2 * 8 + kk];                   \
                const double h3 = (double)hbuf[3 * 8 + kk];                   \
                const double a0 = (double)wv[kk].x;                           \
                const double a1 = (double)wv[kk].y;                           \
                const double a2 = (double)wv[kk].z;                           \
                const double a3 = (double)wv[kk].w;                           \
                acc[0][0] = fma(a0, h0, acc[0][0]);                           \
                acc[0][1] = fma(a0, h1, acc[0][1]);                           \
                acc[0][2] = fma(a0, h2, acc[0][2]);                           \
                acc[0][3] = fma(a0, h3, acc[0][3]);                           \
                acc[1][0] = fma(a1, h0, acc[1][0]);                           \
                acc[1][1] = fma(a1, h1, acc[1][1]);                           \
                acc[1][2] = fma(a1, h2, acc[1][2]);                           \
                acc[1][3] = fma(a1, h3, acc[1][3]);                           \
                acc[2][0] = fma(a2, h0, acc[2][0]);                           \
                acc[2][1] = fma(a2, h1, acc[2][1]);                           \
                acc[2][2] = fma(a2, h2, acc[2][2]);                           \
                acc[2][3] = fma(a2, h3, acc[2][3]);                           \
                acc[3][0] = fma(a3, h0, acc[3][0]);                           \
                acc[3][1] = fma(a3, h1, acc[3][1]);                           \
                acc[3][2] = fma(a3, h2, acc[3][2]);                           \
                acc[3][3] = fma(a3, h3, acc[3][3]);                           \
            }                                                                 \
        } while (0)

    LOADW(wA, 0);
    LOADH(hA, 0);
    for (int kc = 0; kc < H_; kc += 16) {
        LOADW(wB, kc + 8);                   // prefetch next chunk
        LOADH(hB, kc + 8);
        COMPUTE(wA, hA);                     // 512-cy FMA window
        if (kc + 16 < H_) {
            LOADW(wA, kc + 16);
            LOADH(hA, kc + 16);
        }
        COMPUTE(wB, hB);
    }
    #undef LOADW
    #undef LOADH
    #undef COMPUTE

    // Epilogue: bias + silu + w2-dot over this lane's 4 o's.
    const float4 b1v = *reinterpret_cast<const float4*>(b1 + o0);
    const float4 w2v = *reinterpret_cast<const float4*>(w2 + o0);
    double psum[4] = {0.0, 0.0, 0.0, 0.0};
    #define EPI(j, bc, wc)                                                    \
        do {                                                                  \
            const double bb = (double)bc, ww = (double)wc;                    \
            _Pragma("unroll")                                                 \
            for (int r = 0; r < 4; ++r) {                                     \
                const double u = acc[j][r] + bb;                              \
                psum[r] += ww * (u / (1.0 + exp(-u)));                        \
            }                                                                 \
        } while (0)
    EPI(0, b1v.x, w2v.x);
    EPI(1, b1v.y, w2v.y);
    EPI(2, b1v.z, w2v.z);
    EPI(3, b1v.w, w2v.w);
    #undef EPI

    // Full-wave reduce (64 lanes cover all 256 o's); lane 0 writes s.
    #pragma unroll
    for (int r = 0; r < 4; ++r) {
        double v = psum[r];
        v += __shfl_xor(v, 1, 64);
        v += __shfl_xor(v, 2, 64);
        v += __shfl_xor(v, 4, 64);
        v += __shfl_xor(v, 8, 64);
        v += __shfl_xor(v, 16, 64);
        v += __shfl_xor(v, 32, 64);
        if (lane == 0) s_out[m0 + r] = v;
    }
}

// Kernel B: out[b,i,j] = (int32)trunc( (s[b,i] - s[b,j]) + b2 )
__global__ __launch_bounds__(256)
void pair_kernel(const double* __restrict__ s, const float* __restrict__ b2p,
                 int* __restrict__ out) {
    const double b2 = (double)b2p[0];
    const unsigned total4 = (unsigned)(B_) * (unsigned)(N_) * (unsigned)(N_) / 4u;
    const unsigned stride = gridDim.x * blockDim.x;
    for (unsigned idx = blockIdx.x * blockDim.x + threadIdx.x; idx < total4;
         idx += stride) {
        const unsigned base = idx * 4u;                 // element index, %4==0
        const unsigned bi  = base >> 22;                // / (N*N), N*N = 2^22
        const unsigned rem = base & ((1u << 22) - 1u);
        const unsigned i   = rem >> 11;                 // / N
        const unsigned j   = rem & (N_ - 1u);
        const double si = s[bi * N_ + i];
        const double* sp = s + bi * N_ + j;             // 32B aligned (j%4==0)
        const double sj0 = sp[0], sj1 = sp[1], sj2 = sp[2], sj3 = sp[3];
        int4 o;
        o.x = (int)trunc((si - sj0) + b2);
        o.y = (int)trunc((si - sj1) + b2);
        o.z = (int)trunc((si - sj2) + b2);
        o.w = (int)trunc((si - sj3) + b2);
        *reinterpret_cast<int4*>(out + base) = o;
    }
}

extern "C" void kernel_launch(void* const* d_in, const int* in_sizes, int n_in,
                              void* d_out, int out_size, void* d_ws, size_t ws_size,
                              hipStream_t stream) {
    const float* hp = (const float*)d_in[0];
    // d_in[1] = node_mask (unused), d_in[2] = n_nodes (unused)
    const float* W1 = (const float*)d_in[3];
    const float* b1 = (const float*)d_in[4];
    const float* w2 = (const float*)d_in[5];
    const float* b2 = (const float*)d_in[6];

    float* W1T = (float*)d_ws;                                     // 256 KB
    double* s  = (double*)((char*)d_ws + H_ * H_ * sizeof(float)); // 128 KB
    int* out = (int*)d_out;

    transpose_w1<<<H_, H_, 0, stream>>>(W1, W1T);
    s_kernel<<<(B_ * N_) / 16, 256, 0, stream>>>(hp, W1T, b1, w2, s);
    pair_kernel<<<2048, 256, 0, stream>>>(s, b2, out);
}